// Round 1
// baseline (39043.109 us; speedup 1.0000x reference)
//
#include <hip/hip_runtime.h>
#include <math.h>

#define B_   64
#define S_   2048
#define I_   256
#define H_   512
#define K_   768      // I_ + H_
#define G3   1536     // 3*H_

#define NBLK 256      // one WG per CU
#define NTHR 384      // 6 waves
#define ROWS 16       // batch rows per WG  (4 row-groups)
#define COLS 24       // gate cols per WG = 3 regions * 8 h-cols (64 col-groups)
#define HC   8        // h-cols per WG
#define LDA  772      // padded LDS row stride in floats (16B-aligned rows)

#define W_OFF 0
#define A_OFF (COLS * LDA)                 // 18528
#define G_OFF (A_OFF + ROWS * LDA)         // 30880
#define SMEM_FLOATS (G_OFF + 3 * ROWS * HC)  // 31264
#define SMEM_BYTES  (SMEM_FLOATS * 4)        // 125056 B  (<160 KiB, 1 WG/CU)

// Build Vt[c][k] = column-major-transposed [W; U]: Vt is (1536 x 768), k-contiguous.
__global__ __launch_bounds__(256) void prep_transpose(
    const float* __restrict__ W,   // (256, 1536)
    const float* __restrict__ U,   // (512, 1536)
    float* __restrict__ Vt)        // (1536, 768)
{
    const int c = blockIdx.y;
    const int k = blockIdx.x * 256 + threadIdx.x;
    if (k < K_) {
        float v = (k < I_) ? W[(size_t)k * G3 + c] : U[(size_t)(k - I_) * G3 + c];
        Vt[(size_t)c * K_ + k] = v;
    }
}

// DPP rotate-add within 16-lane rows (VALU pipe; avoids loading the LDS pipe).
template <int CTRL>
__device__ __forceinline__ float dpp_add(float v) {
    int r = __builtin_amdgcn_update_dpp(0, __float_as_int(v), CTRL, 0xF, 0xF, false);
    return v + __int_as_float(r);
}

__global__ __launch_bounds__(NTHR, 2) void lstm_persist(
    const float* __restrict__ x,      // (B, S, I)
    const float* __restrict__ bias,   // (3H)
    const float* __restrict__ Vt,     // (G3, K_)
    float* __restrict__ h0,           // ping (zeroed)
    float* __restrict__ h1,           // pong
    float* __restrict__ hidden,       // (B, S, H)
    float* __restrict__ hf,           // (B, H)
    float* __restrict__ cf,           // (B, H)
    unsigned* __restrict__ flags,     // [NBLK], zeroed
    unsigned* __restrict__ gen)       // [1], zeroed
{
    extern __shared__ float smem[];
    float* Wlds = smem + W_OFF;   // [COLS][LDA]  persistent weights
    float* Alds = smem + A_OFF;   // [ROWS][LDA]  [x_t | h] staging
    float* gt   = smem + G_OFF;   // [3][ROWS][HC] gate exchange

    const int tid = threadIdx.x;
    const int bid = blockIdx.x;
    const int rg  = bid & 3;           // row group (aligned with XCD stride 8 -> L2 reuse)
    const int cgp = bid >> 2;          // 0..63 col group
    const int r0  = rg * ROWS;
    const int j0  = cgp * HC;

    // ---- load this WG's 24 weight rows into LDS (once) ----
    for (int f4 = tid; f4 < COLS * (K_ / 4); f4 += NTHR) {
        const int cc  = f4 / (K_ / 4);      // 0..23 = region*8 + cl
        const int kf4 = f4 % (K_ / 4);
        const int region = cc >> 3;
        const int cl  = cc & 7;
        const float4 v = *(const float4*)(Vt + (size_t)(region * H_ + j0 + cl) * K_ + kf4 * 4);
        *(float4*)(Wlds + cc * LDA + kf4 * 4) = v;
    }
    // ---- prestage x-part for t=0 ----
    for (int f4 = tid; f4 < ROWS * (I_ / 4); f4 += NTHR) {
        const int r = f4 >> 6, kf4 = f4 & 63;
        const float4 v = *(const float4*)(x + (size_t)(r0 + r) * ((size_t)S_ * I_) + kf4 * 4);
        *(float4*)(Alds + r * LDA + kf4 * 4) = v;
    }

    // compute mapping: 12 tiles (2 row-tiles x 6 col-tiles) x 32-way K split
    const int ks   = tid & 31;
    const int tile = tid >> 5;          // 0..11
    const int tr   = tile / 6;          // 0..1 : rows tr*8..tr*8+7
    const int tc   = tile % 6;          // 0..5 : weight rows tc*4..tc*4+3
    const int rw0  = tr * 8;

    float bi = 0.f, bg = 0.f, bo = 0.f;
    if (tid < ROWS * HC) {
        const int cl = tid & 7;
        bi = bias[0 * H_ + j0 + cl];
        bg = bias[1 * H_ + j0 + cl];
        bo = bias[2 * H_ + j0 + cl];
    }

    float* hprev = h0;
    float* hnext = h1;
    unsigned budget = 2000000u;   // spin-budget: degrade instead of hanging

    #pragma unroll 1
    for (int t = 0; t < S_; ++t) {
        // ---- stage h-part of A (reads hprev; t=0 reads zeroed h0) ----
        for (int f4 = tid; f4 < ROWS * (H_ / 4); f4 += NTHR) {
            const int r = f4 >> 7, jf4 = f4 & 127;
            const float4 v = *(const float4*)(hprev + (size_t)(r0 + r) * H_ + jf4 * 4);
            *(float4*)(Alds + r * LDA + I_ + jf4 * 4) = v;
        }
        __syncthreads();

        // ---- register-blocked dots: 8 rows x 4 cols per thread, K split by 32 lanes ----
        float acc[8][4];
        #pragma unroll
        for (int i = 0; i < 8; ++i) { acc[i][0] = 0.f; acc[i][1] = 0.f; acc[i][2] = 0.f; acc[i][3] = 0.f; }

        #pragma unroll
        for (int j = 0; j < 6; ++j) {
            const int kk = ks * 4 + j * 128;
            const float4 w0 = *(const float4*)(Wlds + (tc * 4 + 0) * LDA + kk);
            const float4 w1 = *(const float4*)(Wlds + (tc * 4 + 1) * LDA + kk);
            const float4 w2 = *(const float4*)(Wlds + (tc * 4 + 2) * LDA + kk);
            const float4 w3 = *(const float4*)(Wlds + (tc * 4 + 3) * LDA + kk);
            #pragma unroll
            for (int i = 0; i < 8; ++i) {
                const float4 a = *(const float4*)(Alds + (rw0 + i) * LDA + kk);
                acc[i][0] += a.x * w0.x + a.y * w0.y + a.z * w0.z + a.w * w0.w;
                acc[i][1] += a.x * w1.x + a.y * w1.y + a.z * w1.z + a.w * w1.w;
                acc[i][2] += a.x * w2.x + a.y * w2.y + a.z * w2.z + a.w * w2.w;
                acc[i][3] += a.x * w3.x + a.y * w3.y + a.z * w3.z + a.w * w3.w;
            }
        }

        // ---- reduce across the 32 K-split lanes: DPP within 16, shfl across 16 ----
        #pragma unroll
        for (int i = 0; i < 8; ++i) {
            #pragma unroll
            for (int c = 0; c < 4; ++c) {
                float v = acc[i][c];
                v = dpp_add<0x121>(v);   // row_ror:1
                v = dpp_add<0x122>(v);   // row_ror:2
                v = dpp_add<0x124>(v);   // row_ror:4
                v = dpp_add<0x128>(v);   // row_ror:8  -> full 16-lane sum
                v += __shfl_xor(v, 16, 32);
                acc[i][c] = v;
            }
        }
        if (ks == 0) {
            const int region = tc >> 1;
            const int cl0 = (tc & 1) * 4;
            #pragma unroll
            for (int i = 0; i < 8; ++i) {
                *(float4*)(gt + region * (ROWS * HC) + (rw0 + i) * HC + cl0) =
                    make_float4(acc[i][0], acc[i][1], acc[i][2], acc[i][3]);
            }
        }
        __syncthreads();

        // ---- waves 0-1: activations + stores; waves 2-5: prestage x(t+1) ----
        if (tid < ROWS * HC) {
            const int r = tid >> 3, cl = tid & 7;
            const float gi = gt[0 * (ROWS * HC) + tid] + bi;
            const float gg = gt[1 * (ROWS * HC) + tid] + bg;
            const float go = gt[2 * (ROWS * HC) + tid] + bo;
            const float it = 1.f / (1.f + __expf(-gi));
            const float g2 = tanhf(gg);
            const float ot = 1.f / (1.f + __expf(-go));
            const float ct = it * g2;
            const float ht = ot * tanhf(ct);
            const int rr = r0 + r, jj = j0 + cl;
            hnext[(size_t)rr * H_ + jj] = ht;
            hidden[(size_t)rr * ((size_t)S_ * H_) + (size_t)t * H_ + jj] = ht;
            if (t == S_ - 1) {
                hf[(size_t)rr * H_ + jj] = ht;
                cf[(size_t)rr * H_ + jj] = ct;
            }
        } else if (t + 1 < S_) {
            for (int f4 = tid - 128; f4 < ROWS * (I_ / 4); f4 += (NTHR - 128)) {
                const int r = f4 >> 6, kf4 = f4 & 63;
                const float4 v = *(const float4*)(x + (size_t)(r0 + r) * ((size_t)S_ * I_)
                                                  + (size_t)(t + 1) * I_ + kf4 * 4);
                *(float4*)(Alds + r * LDA + kf4 * 4) = v;
            }
        }

        // ---- grid barrier: flags -> (WG0 gathers) -> gen ----
        __syncthreads();   // drains each wave's stores to L2 (vmcnt0 before s_barrier)
        const unsigned target = (unsigned)(t + 1);
        if (tid == 0) {
            __threadfence();  // agent release: wb L2 so h reaches LLC
            __hip_atomic_store(flags + bid, target, __ATOMIC_RELAXED, __HIP_MEMORY_SCOPE_AGENT);
        }
        if (bid == 0) {
            for (int i = tid; i < NBLK; i += NTHR) {
                while (__hip_atomic_load(flags + i, __ATOMIC_RELAXED, __HIP_MEMORY_SCOPE_AGENT) < target) {
                    if (budget == 0) break;
                    --budget;
                }
            }
            __syncthreads();
            if (tid == 0) {
                __threadfence();
                __hip_atomic_store(gen, target, __ATOMIC_RELAXED, __HIP_MEMORY_SCOPE_AGENT);
            }
        }
        if (tid == 0) {
            while (__hip_atomic_load(gen, __ATOMIC_RELAXED, __HIP_MEMORY_SCOPE_AGENT) < target) {
                if (budget == 0) break;
                --budget;
            }
            __threadfence();  // agent acquire: inv L1/L2 so fresh h is read next step
        }
        __syncthreads();

        float* tmp = hprev; hprev = hnext; hnext = tmp;
    }
}

extern "C" void kernel_launch(void* const* d_in, const int* in_sizes, int n_in,
                              void* d_out, int out_size, void* d_ws, size_t ws_size,
                              hipStream_t stream) {
    (void)in_sizes; (void)n_in; (void)out_size; (void)ws_size;
    const float* x    = (const float*)d_in[0];
    const float* W    = (const float*)d_in[1];
    const float* U    = (const float*)d_in[2];
    const float* bias = (const float*)d_in[3];

    float* out    = (float*)d_out;
    float* hidden = out;                                   // B*S*H
    float* hf     = out + (size_t)B_ * S_ * H_;
    float* cf     = hf + (size_t)B_ * H_;

    // workspace: Vt (1536*768 f32) | h ping | h pong | flags[256] .. gen
    float* Vt = (float*)d_ws;
    float* h0 = Vt + (size_t)G3 * K_;
    float* h1 = h0 + (size_t)B_ * H_;
    unsigned* flags = (unsigned*)(h1 + (size_t)B_ * H_);
    unsigned* gen   = flags + 320;                          // own cacheline region

    hipLaunchKernelGGL(prep_transpose, dim3(3, G3), dim3(256), 0, stream, W, U, Vt);
    hipMemsetAsync(h0, 0, (size_t)B_ * H_ * sizeof(float), stream);
    hipMemsetAsync(flags, 0, 384 * sizeof(unsigned), stream);  // covers flags + gen

    static int attr_set = 0;
    if (!attr_set) {
        hipFuncSetAttribute((const void*)lstm_persist,
                            hipFuncAttributeMaxDynamicSharedMemorySize, SMEM_BYTES);
        attr_set = 1;
    }

    void* args[] = { (void*)&x, (void*)&bias, (void*)&Vt, (void*)&h0, (void*)&h1,
                     (void*)&hidden, (void*)&hf, (void*)&cf, (void*)&flags, (void*)&gen };
    hipLaunchCooperativeKernel((const void*)lstm_persist, dim3(NBLK), dim3(NTHR),
                               args, SMEM_BYTES, stream);
}